// Round 3
// baseline (430.277 us; speedup 1.0000x reference)
//
#include <hip/hip_runtime.h>
#include <hip/hip_bf16.h>
#include <math.h>

// Problem: bs=8, seq=2048, d_in=d_out=2048, R=8, ctr_out=32, ctr_final=4
// ws layout (floats): A[8*8*2048] | B[8*8*2048]  (B has SCALING folded in)

#define BS 8
#define SEQ 2048
#define DIM 2048
#define RR 8
#define SCALING 2.0f   // 16.0 / R

// ---------------------------------------------------------------------------
// Kernel 1: gating MLP + A/B generation (tiny; unchanged from round 2).
// ---------------------------------------------------------------------------
__global__ void gate_ab_kernel(const float* __restrict__ ctr,
                               const float* __restrict__ gamma,
                               const float* __restrict__ beta,
                               const float* __restrict__ W1,
                               const float* __restrict__ b1,
                               const float* __restrict__ W2,
                               const float* __restrict__ b2,
                               const float* __restrict__ Wa,
                               const float* __restrict__ Wb,
                               float* __restrict__ A,
                               float* __restrict__ B) {
    __shared__ float z_s[BS][32];
    __shared__ float h_s[BS][60];
    __shared__ float logit_s[BS][4];
    __shared__ float gate_s[BS][4];
    const int tid = threadIdx.x;

    {
        const int b = tid >> 5, i = tid & 31;
        float v = ctr[b * 32 + i];
        float s = v;
        #pragma unroll
        for (int m = 16; m; m >>= 1) s += __shfl_xor(s, m, 64);
        const float mu = s * (1.0f / 32.0f);
        const float d = v - mu;
        float sq = d * d;
        #pragma unroll
        for (int m = 16; m; m >>= 1) sq += __shfl_xor(sq, m, 64);
        const float var = sq * (1.0f / 32.0f);
        z_s[b][i] = d * rsqrtf(var + 1e-5f) * gamma[i] + beta[i];
    }
    __syncthreads();

    for (int idx = tid; idx < BS * 60; idx += 256) {
        const int b = idx / 60, j = idx % 60;
        float acc = b1[j];
        #pragma unroll
        for (int k = 0; k < 32; ++k) acc += z_s[b][k] * W1[j * 32 + k];
        h_s[b][j] = fmaxf(acc, 0.0f);
    }
    __syncthreads();

    if (tid < 32) {
        const int b = tid >> 2, c = tid & 3;
        float acc = b2[c];
        for (int k = 0; k < 60; ++k) acc += h_s[b][k] * W2[c * 60 + k];
        logit_s[b][c] = acc;
    }
    __syncthreads();

    if (tid < 8) {
        float m = logit_s[tid][0];
        #pragma unroll
        for (int c = 1; c < 4; ++c) m = fmaxf(m, logit_s[tid][c]);
        float e[4], s = 0.0f;
        #pragma unroll
        for (int c = 0; c < 4; ++c) { e[c] = expf(logit_s[tid][c] - m); s += e[c]; }
        const float inv = 1.0f / s;
        #pragma unroll
        for (int c = 0; c < 4; ++c) gate_s[tid][c] = e[c] * inv;
    }
    __syncthreads();

    const float4* __restrict__ Wa4 = (const float4*)Wa;
    const float4* __restrict__ Wb4 = (const float4*)Wb;
    const int total = BS * RR * DIM;   // 131072
    for (int idx = blockIdx.x * 256 + tid; idx < total; idx += gridDim.x * 256) {
        const int b = idx >> 14, rd = idx & 16383;
        const float4 g = *(const float4*)gate_s[b];
        const float4 wa = Wa4[rd];
        A[idx] = g.x * wa.x + g.y * wa.y + g.z * wa.z + g.w * wa.w;
        const float4 wb = Wb4[rd];
        B[idx] = SCALING * (g.x * wb.x + g.y * wb.y + g.z * wb.z + g.w * wb.w);
    }
}

// ---------------------------------------------------------------------------
// Fused kernel, LDS-free. Each wave owns 2 seq rows:
//   phase 1: acc[i][r] = partial dot over this lane's d-slice, A read straight
//            from global (L1/L2-hot: all blocks on a CU share the same b)
//   butterfly __shfl_xor -> every lane holds xa[i][r]
//   phase 2: out[i][o-slice] = sum_r xa[i][r]*B[r][o], B from L1/L2
// No barriers, no LDS -> occupancy limited only by VGPRs (~24 waves/CU).
// 2048 blocks of 256 threads (4 waves * 2 rows = 8 rows/block).
// ---------------------------------------------------------------------------
__global__ void __launch_bounds__(256, 6)
fused_kernel(const float* __restrict__ x, const float* __restrict__ A,
             const float* __restrict__ B, float* __restrict__ out) {
    const int b = blockIdx.x >> 8;          // 256 blocks per batch
    const int tile = blockIdx.x & 255;      // 8 rows per block
    const int wave = threadIdx.x >> 6, lane = threadIdx.x & 63;
    const int row = tile * 8 + wave * 2;

    const float* __restrict__ Ag = A + b * (RR * DIM);
    const float* __restrict__ Bg = B + b * (RR * DIM);
    const float* __restrict__ xr = x + ((size_t)b * SEQ + row) * DIM;

    float acc[2][8];
    #pragma unroll
    for (int i = 0; i < 2; ++i)
        #pragma unroll
        for (int r = 0; r < 8; ++r) acc[i][r] = 0.0f;

    // ---- phase 1: partial dots, x prefetched 1 j-iter deep ----
    float4 xc[2], xn[2];
    {
        const int d0 = lane * 4;
        xc[0] = *(const float4*)&xr[d0];
        xc[1] = *(const float4*)&xr[DIM + d0];
    }
    #pragma unroll
    for (int j = 0; j < 8; ++j) {
        const int d = j * 256 + lane * 4;
        if (j < 7) {
            xn[0] = *(const float4*)&xr[d + 256];
            xn[1] = *(const float4*)&xr[DIM + d + 256];
        }
        float4 a4[8];
        #pragma unroll
        for (int r = 0; r < 8; ++r) a4[r] = *(const float4*)&Ag[r * DIM + d];
        #pragma unroll
        for (int i = 0; i < 2; ++i) {
            #pragma unroll
            for (int r = 0; r < 8; ++r)
                acc[i][r] += xc[i].x * a4[r].x + xc[i].y * a4[r].y +
                             xc[i].z * a4[r].z + xc[i].w * a4[r].w;
        }
        xc[0] = xn[0];
        xc[1] = xn[1];
    }

    // ---- butterfly reduce: every lane ends with full xa[i][r] ----
    #pragma unroll
    for (int i = 0; i < 2; ++i)
        #pragma unroll
        for (int r = 0; r < 8; ++r) {
            float v = acc[i][r];
            #pragma unroll
            for (int off = 32; off; off >>= 1) v += __shfl_xor(v, off, 64);
            acc[i][r] = v;
        }

    // ---- phase 2: out = xa . B ----
    float* __restrict__ ob = out + ((size_t)b * SEQ + row) * DIM;
    #pragma unroll
    for (int j = 0; j < 8; ++j) {
        const int o = j * 256 + lane * 4;
        float4 b4[8];
        #pragma unroll
        for (int r = 0; r < 8; ++r) b4[r] = *(const float4*)&Bg[r * DIM + o];
        #pragma unroll
        for (int i = 0; i < 2; ++i) {
            float4 v = {0.0f, 0.0f, 0.0f, 0.0f};
            #pragma unroll
            for (int r = 0; r < 8; ++r) {
                v.x += acc[i][r] * b4[r].x;
                v.y += acc[i][r] * b4[r].y;
                v.z += acc[i][r] * b4[r].z;
                v.w += acc[i][r] * b4[r].w;
            }
            *(float4*)&ob[(size_t)i * DIM + o] = v;
        }
    }
}

extern "C" void kernel_launch(void* const* d_in, const int* in_sizes, int n_in,
                              void* d_out, int out_size, void* d_ws, size_t ws_size,
                              hipStream_t stream) {
    const float* x     = (const float*)d_in[0];
    const float* ctr   = (const float*)d_in[1];
    const float* gamma = (const float*)d_in[2];
    const float* beta  = (const float*)d_in[3];
    const float* W1    = (const float*)d_in[4];
    const float* b1    = (const float*)d_in[5];
    const float* W2    = (const float*)d_in[6];
    const float* b2    = (const float*)d_in[7];
    const float* Wa    = (const float*)d_in[8];
    const float* Wb    = (const float*)d_in[9];

    float* ws = (float*)d_ws;
    float* A  = ws;                  // 131072 floats
    float* B  = ws + 131072;         // 131072 floats
    float* out = (float*)d_out;

    gate_ab_kernel<<<128, 256, 0, stream>>>(ctr, gamma, beta, W1, b1, W2, b2,
                                            Wa, Wb, A, B);
    fused_kernel<<<2048, 256, 0, stream>>>(x, A, B, out);
}